// Round 17
// baseline (107.942 us; speedup 1.0000x reference)
//
#include <hip/hip_runtime.h>
#include <math.h>

typedef unsigned short u16;
typedef unsigned int u32;
typedef __bf16 bf16x8 __attribute__((ext_vector_type(8)));
typedef float f32x4 __attribute__((ext_vector_type(4)));
typedef unsigned short ushort4v __attribute__((ext_vector_type(4)));

#define T_SEQ 2048
#define WIN_M1 523                 // WINDOW-1
#define QSCALE 0.180336879f        // 0.125 * log2(e): scores end up in log2 domain
#define MASKV -1e30f

__device__ __forceinline__ u16 f2b(float f) {
  union { float f; unsigned int u; } v; v.f = f;
  unsigned int u = v.u;
  u += 0x7FFFu + ((u >> 16) & 1u);
  return (u16)(u >> 16);
}

// Packed f32->bf16 via COMPILER-generated conversion (hazard-safe vs v_exp
// TRANS producers -- R13/R14 lesson).
__device__ __forceinline__ u32 cvtpk(float lo, float hi) {
  union { __bf16 h[2]; u32 d; } cv;
  cv.h[0] = (__bf16)lo;
  cv.h[1] = (__bf16)hi;
  return cv.d;
}

__device__ __forceinline__ float fexp2(float x) {
  return __builtin_amdgcn_exp2f(x);
}

__device__ __forceinline__ void load_lds16(const u16* g, u16* l) {
  __builtin_amdgcn_global_load_lds(
      (const __attribute__((address_space(1))) void*)g,
      (__attribute__((address_space(3))) void*)l, 16, 0, 0);
}

// ===================== FRAGMENT-ORDERED TENSOR LAYOUTS (R16 win) ===========
//   Qf/Kf: [bh][t16=t/16][kb(2)][q4(4)][l15(16)][e(8)]
//   Vf:    [bh][kv32=kv/32][jo(4)][q4(4)][l15(16)][e(8)]
// Every attn load = base + lane*16B -> one contiguous 1KB segment/instr.
// ===========================================================================

// ---- fused prep: convert x (blocks 0..4095) + transpose 4 weights (blocks 4096..8191) ----
__global__ void prep_k(const float* __restrict__ x, u16* __restrict__ xb,
                       const float* __restrict__ W0, const float* __restrict__ W1,
                       const float* __restrict__ W2, const float* __restrict__ W3,
                       u16* __restrict__ WcatT, u16* __restrict__ WoT) {
  const int bid = blockIdx.x;
  if (bid < 4096) {
    int i = bid * 256 + threadIdx.x;
    float4 v = ((const float4*)x)[i];
    u16* d = xb + i * 4;
    d[0] = f2b(v.x); d[1] = f2b(v.y); d[2] = f2b(v.z); d[3] = f2b(v.w);
    return;
  }
  __shared__ float tile[32][33];
  const int t = bid - 4096;
  const int z = t >> 10, i = t & 1023;
  const float* W = (z == 0) ? W0 : (z == 1) ? W1 : (z == 2) ? W2 : W3;
  u16* Wt = (z < 3) ? (WcatT + (size_t)z * 1024 * 1024) : WoT;
  int tx = threadIdx.x & 31, ty = threadIdx.x >> 5;  // 32 x 8
  int n0 = (i & 31) * 32, k0 = (i >> 5) * 32;
#pragma unroll
  for (int j = 0; j < 4; ++j)
    tile[ty + j * 8][tx] = W[(size_t)(k0 + ty + j * 8) * 1024 + n0 + tx];
  __syncthreads();
#pragma unroll
  for (int j = 0; j < 4; ++j)
    Wt[(size_t)(n0 + ty + j * 8) * 1024 + k0 + tx] = f2b(tile[tx][ty + j * 8]);
}

// ---- 128x128 bf16 MFMA GEMM: 8 WAVES/BLOCK (512 thr), 3-buf LDS, depth-2 vmcnt ----
// R17: same 128^2 tile and pipeline as R16, but 8 waves/block (acc[2][4],
// 8 MFMA/step/wave). LDS unchanged (48KB -> 3 blocks/CU), so waves/SIMD
// doubles 3 -> 6 = 3 independent block-streams x 2: the SIMD hides one
// block's vmcnt stall behind the other blocks' compute. Per-wave staging:
// 1 A-chunk + 1 B-chunk (2 loads/step -> vmcnt(4) steady, 2 -> 0 tail).
// MODE 0: A=xb[4096][1024], Bt=WcatT[3072][1024] -> Qf/Kf (rope) + Vf
// MODE 1: A=Y [4096][1024], Bt=WoT [1024][1024] -> out fp32 row-major
template <int MODE>
__global__ __launch_bounds__(512, 6) void gemm_k(
    const u16* __restrict__ A, const u16* __restrict__ Bt,
    float* __restrict__ outf,
    u16* __restrict__ Qo, u16* __restrict__ Ko, u16* __restrict__ Vto,
    const float* __restrict__ rc, const float* __restrict__ rs) {
  __shared__ alignas(16) u16 As[3][128 * 32];
  __shared__ alignas(16) u16 Bs[3][128 * 32];
  const int tid = threadIdx.x, lane = tid & 63, w = tid >> 6;  // w in 0..7
  const int l15 = lane & 15, q4 = lane >> 4;
  const int row0 = blockIdx.y * 128, col0 = blockIdx.x * 128;
  const int wm = w >> 1, wn = w & 1;  // wm 0..3 (32-row span), wn 0..1 (64-col span)
  constexpr int NT = 32;  // K=1024 / 32

  f32x4 acc[2][4];
#pragma unroll
  for (int i = 0; i < 2; ++i)
#pragma unroll
    for (int j = 0; j < 4; ++j) acc[i][j] = (f32x4){0.f, 0.f, 0.f, 0.f};

  // staging: tile [128 rows][32 k] bf16 linear. 8 chunks of 1KB (16 rows);
  // wave w stages chunk w of A and of B. Lane covers 16B:
  // row = w*16 + lane/4, col(u16) = (lane&3)*8.
  const int rs_ = w * 16 + (lane >> 2), cs_ = (lane & 3) * 8;
  const u16* gA0 = A + (size_t)(row0 + rs_) * 1024 + cs_;
  const u16* gB0 = Bt + (size_t)(col0 + rs_) * 1024 + cs_;
  const int soff = w * 512;

  auto stage = [&](int buf, int t) {
    const int k0 = t * 32;
    load_lds16(gA0 + k0, &As[buf][soff]);
    load_lds16(gB0 + k0, &Bs[buf][soff]);
  };
  auto compute = [&](int buf) {
    bf16x8 af[2], bfr[4];
#pragma unroll
    for (int im = 0; im < 2; ++im)
      af[im] = *(const bf16x8*)&As[buf][(wm * 32 + im * 16 + l15) * 32 + q4 * 8];
#pragma unroll
    for (int jn = 0; jn < 4; ++jn)
      bfr[jn] = *(const bf16x8*)&Bs[buf][(wn * 64 + jn * 16 + l15) * 32 + q4 * 8];
#pragma unroll
    for (int im = 0; im < 2; ++im)
#pragma unroll
      for (int jn = 0; jn < 4; ++jn)
        acc[im][jn] = __builtin_amdgcn_mfma_f32_16x16x32_bf16(af[im], bfr[jn], acc[im][jn], 0, 0, 0);
  };

  stage(0, 0);
  stage(1, 1);
  int bs = 2, bc = 0;
  for (int t = 0; t + 2 < NT; ++t) {
    stage(bs, t + 2);
    asm volatile("s_waitcnt vmcnt(4)" ::: "memory");
    __builtin_amdgcn_s_barrier();
    compute(bc);
    __builtin_amdgcn_s_barrier();
    bs = (bs + 1 == 3) ? 0 : bs + 1;
    bc = (bc + 1 == 3) ? 0 : bc + 1;
  }
  asm volatile("s_waitcnt vmcnt(2)" ::: "memory");
  __builtin_amdgcn_s_barrier();
  compute(bc);
  __builtin_amdgcn_s_barrier();
  bc = (bc + 1 == 3) ? 0 : bc + 1;
  asm volatile("s_waitcnt vmcnt(0)" ::: "memory");
  __builtin_amdgcn_s_barrier();
  compute(bc);

  if constexpr (MODE == 0) {
#pragma unroll
    for (int im = 0; im < 2; ++im) {
      const int rowb = row0 + wm * 32 + im * 16 + q4 * 4;
      const int b = rowb >> 11, t0 = rowb & 2047;
#pragma unroll
      for (int jn = 0; jn < 2; ++jn) {
        const int n = col0 + wn * 64 + jn * 16 + l15;
        const int sel = n >> 10, nn = n & 1023;
        const int h = nn >> 6, hd = nn & 63;  // hd = jn*16+l15, in [0,32)
        const int bhi = b * 16 + h;
        if (sel < 2) {
          const float qs = (sel == 0) ? QSCALE : 1.0f;
          u16* base = (sel == 0 ? Qo : Ko);
          const int q4c = (hd >> 3) & 3, e = hd & 7;
#pragma unroll
          for (int r = 0; r < 4; ++r) {
            const int tt = t0 + r;
            const float c = rc[tt * 32 + hd], s = rs[tt * 32 + hd];
            const float x1 = acc[im][jn][r], x2 = acc[im][jn + 2][r];
            const size_t blk = ((size_t)bhi * 128 + (tt >> 4)) * 2;
            const size_t off = (size_t)q4c * 128 + (size_t)(tt & 15) * 8 + e;
            base[(blk << 9) + off] = f2b((x1 * c + x2 * s) * qs);
            base[((blk + 1) << 9) + off] = f2b((x1 * c - x2 * s) * qs);
          }
        } else {
          const int kv32 = t0 >> 5;
          const int q4w = (t0 >> 3) & 3;
          const int e0 = t0 & 7;           // in {0,4}
          const int jo1 = hd >> 4;         // = jn
          const int l15r = hd & 15;        // = l15
          ushort4v p1, p2;
#pragma unroll
          for (int r = 0; r < 4; ++r) {
            p1[r] = f2b(acc[im][jn][r]);
            p2[r] = f2b(acc[im][jn + 2][r]);
          }
          const size_t off = (size_t)q4w * 128 + (size_t)l15r * 8 + e0;
          const size_t b1 = ((((size_t)bhi * 64 + kv32) * 4 + jo1) << 9) + off;
          const size_t b2 = ((((size_t)bhi * 64 + kv32) * 4 + jo1 + 2) << 9) + off;
          *(ushort4v*)(Vto + b1) = p1;
          *(ushort4v*)(Vto + b2) = p2;
        }
      }
    }
  } else {
#pragma unroll
    for (int im = 0; im < 2; ++im) {
      const int rowb = row0 + wm * 32 + im * 16 + q4 * 4;
#pragma unroll
      for (int jn = 0; jn < 4; ++jn) {
        const int n = col0 + wn * 64 + jn * 16 + l15;
#pragma unroll
        for (int r = 0; r < 4; ++r)
          outf[(size_t)(rowb + r) * 1024 + n] = acc[im][jn][r];
      }
    }
  }
}

// ---------------- windowed flash attention (R16 winner, unchanged) ----------------
// Qf,Kf,Vf fragment-ordered. 4 waves/block, 32 q-rows/wave, KV tile 32, no
// LDS, K/V prefetch distance 1, fixed-max softmax, raw v_exp, shuffle
// P-relayout, K=32 PV. All loads contiguous 1KB/instr.
__global__ __launch_bounds__(256) void attn_k(
    const u16* __restrict__ Q, const u16* __restrict__ Kk,
    const u16* __restrict__ Vt, u16* __restrict__ Y) {
  const int lane = threadIdx.x & 63, w = threadIdx.x >> 6;
  const int l15 = lane & 15, q4 = lane >> 4;
  const int hw = blockIdx.x;                    // 0..511
  const int work = (hw & 7) * 64 + (hw >> 3);   // XCD-chunked: each XCD owns 4 bh
  const int bh = work >> 4;
  const int qt = 15 - (work & 15);              // heavy (large window) first
  const int q0 = qt * 128 + w * 32;
  const int qt16 = q0 >> 4;

  bf16x8 bq[2][2];
#pragma unroll
  for (int qs = 0; qs < 2; ++qs)
#pragma unroll
    for (int kb = 0; kb < 2; ++kb)
      bq[qs][kb] = *(const bf16x8*)(Q + ((((size_t)bh * 128 + qt16 + qs) * 2 + kb) << 9) + lane * 8);

  f32x4 o[2][4];
#pragma unroll
  for (int qs = 0; qs < 2; ++qs)
#pragma unroll
    for (int jo = 0; jo < 4; ++jo) o[qs][jo] = (f32x4){0.f, 0.f, 0.f, 0.f};
  float lp[2] = {0.f, 0.f};

  int s0 = q0 - WIN_M1; if (s0 < 0) s0 = 0; s0 &= ~31;
  const int srcA = l15 + ((q4 & 1) << 5);
  const int srcB = srcA + 16;
  const bool lowq4 = (q4 < 2);

  bf16x8 kc[2][2], kn[2][2];
  bf16x8 vc[4], vn[4];
#pragma unroll
  for (int ks = 0; ks < 2; ++ks)
#pragma unroll
    for (int kb = 0; kb < 2; ++kb)
      kc[ks][kb] = *(const bf16x8*)(Kk + ((((size_t)bh * 128 + (s0 >> 4) + ks) * 2 + kb) << 9) + lane * 8);
#pragma unroll
  for (int jo = 0; jo < 4; ++jo)
    vc[jo] = *(const bf16x8*)(Vt + ((((size_t)bh * 64 + (s0 >> 5)) * 4 + jo) << 9) + lane * 8);

  int kv0 = s0;

#define TILE_BODY(KC, VC, KN, VN)                                                      \
  {                                                                                    \
    const int kvn = kv0 + 32;                                                          \
    if (kvn <= q0) {                                                                   \
      _Pragma("unroll") for (int ks = 0; ks < 2; ++ks)                                 \
          _Pragma("unroll") for (int kb = 0; kb < 2; ++kb)                             \
              KN[ks][kb] = *(const bf16x8*)(Kk +                                       \
                  ((((size_t)bh * 128 + (kvn >> 4) + ks) * 2 + kb) << 9) + lane * 8);  \
      _Pragma("unroll") for (int jo = 0; jo < 4; ++jo)                                 \
          VN[jo] = *(const bf16x8*)(Vt +                                               \
              ((((size_t)bh * 64 + (kvn >> 5)) * 4 + jo) << 9) + lane * 8);            \
    }                                                                                  \
    f32x4 ss[2][2];                                                                    \
    _Pragma("unroll") for (int ks = 0; ks < 2; ++ks)                                   \
        _Pragma("unroll") for (int qs = 0; qs < 2; ++qs)                               \
            ss[ks][qs] = (f32x4){0.f, 0.f, 0.f, 0.f};                                  \
    _Pragma("unroll") for (int kb = 0; kb < 2; ++kb)                                   \
        _Pragma("unroll") for (int ks = 0; ks < 2; ++ks)                               \
            _Pragma("unroll") for (int qs = 0; qs < 2; ++qs)                           \
                ss[ks][qs] = __builtin_amdgcn_mfma_f32_16x16x32_bf16(                  \
                    KC[ks][kb], bq[qs][kb], ss[ks][qs], 0, 0, 0);                      \
    if ((kv0 + 32 > q0) || (kv0 < q0 - 492)) {                                         \
      _Pragma("unroll") for (int qs = 0; qs < 2; ++qs) {                               \
        const int tq = q0 + qs * 16 + l15;                                             \
        _Pragma("unroll") for (int ks = 0; ks < 2; ++ks)                               \
            _Pragma("unroll") for (int r = 0; r < 4; ++r) {                            \
          const int kv = kv0 + ks * 16 + q4 * 4 + r;                                   \
          if (kv > tq || kv < tq - WIN_M1) ss[ks][qs][r] = MASKV;                      \
        }                                                                              \
      }                                                                                \
    }                                                                                  \
    _Pragma("unroll") for (int qs = 0; qs < 2; ++qs) {                                 \
      float p[2][4];                                                                   \
      _Pragma("unroll") for (int ks = 0; ks < 2; ++ks)                                 \
          _Pragma("unroll") for (int r = 0; r < 4; ++r)                                \
              p[ks][r] = fexp2(ss[ks][qs][r]);                                         \
      lp[qs] += ((p[0][0] + p[0][1]) + (p[0][2] + p[0][3])) +                          \
                ((p[1][0] + p[1][1]) + (p[1][2] + p[1][3]));                           \
      const u32 a0 = cvtpk(p[0][0], p[0][1]), a1 = cvtpk(p[0][2], p[0][3]);            \
      const u32 b0 = cvtpk(p[1][0], p[1][1]), b1 = cvtpk(p[1][2], p[1][3]);            \
      union { u32 d[4]; bf16x8 v; } pu;                                                \
      const u32 d0a = (u32)__shfl((int)a0, srcA), d0b = (u32)__shfl((int)b0, srcA);    \
      const u32 d1a = (u32)__shfl((int)a1, srcA), d1b = (u32)__shfl((int)b1, srcA);    \
      const u32 d2a = (u32)__shfl((int)a0, srcB), d2b = (u32)__shfl((int)b0, srcB);    \
      const u32 d3a = (u32)__shfl((int)a1, srcB), d3b = (u32)__shfl((int)b1, srcB);    \
      pu.d[0] = lowq4 ? d0a : d0b;                                                     \
      pu.d[1] = lowq4 ? d1a : d1b;                                                     \
      pu.d[2] = lowq4 ? d2a : d2b;                                                     \
      pu.d[3] = lowq4 ? d3a : d3b;                                                     \
      _Pragma("unroll") for (int jo = 0; jo < 4; ++jo)                                 \
          o[qs][jo] = __builtin_amdgcn_mfma_f32_16x16x32_bf16(pu.v, VC[jo],            \
                                                              o[qs][jo], 0, 0, 0);     \
    }                                                                                  \
  }

  while (true) {
    TILE_BODY(kc, vc, kn, vn);
    kv0 += 32; if (kv0 > q0) break;
    TILE_BODY(kn, vn, kc, vc);
    kv0 += 32; if (kv0 > q0) break;
  }
#undef TILE_BODY

  const int b = bh >> 4, h = bh & 15;
  u16* Yb = Y + (size_t)(b * 2048 + q0) * 1024 + h * 64 + l15;
#pragma unroll
  for (int qs = 0; qs < 2; ++qs) {
    float l = lp[qs];
    l += __shfl_xor(l, 16);
    l += __shfl_xor(l, 32);
#pragma unroll
    for (int r = 0; r < 4; ++r) {
      const float lv = __shfl(l, q4 * 4 + r);
      const float inv = 1.0f / lv;
      u16* yr = Yb + (size_t)(qs * 16 + q4 * 4 + r) * 1024;
#pragma unroll
      for (int jo = 0; jo < 4; ++jo) yr[jo * 16] = f2b(o[qs][jo][r] * inv);
    }
  }
}

extern "C" void kernel_launch(void* const* d_in, const int* in_sizes, int n_in,
                              void* d_out, int out_size, void* d_ws, size_t ws_size,
                              hipStream_t stream) {
  const float* x = (const float*)d_in[0];
  const float* Wq = (const float*)d_in[1];
  const float* Wk = (const float*)d_in[2];
  const float* Wv = (const float*)d_in[3];
  const float* Wo = (const float*)d_in[4];
  const float* rc = (const float*)d_in[5];
  const float* rs = (const float*)d_in[6];
  float* out = (float*)d_out;
  char* ws = (char*)d_ws;
  const size_t MB = 1024 * 1024;
  u16* xb = (u16*)(ws);              // [4096][1024] 8MB
  u16* WcatT = (u16*)(ws + 8 * MB);  // [3072][1024] 6MB (Wq^T|Wk^T|Wv^T)
  u16* WoT = (u16*)(ws + 14 * MB);   // [1024][1024] 2MB
  u16* Qf = (u16*)(ws + 16 * MB);    // fragment-ordered Q, 8MB
  u16* Kf = (u16*)(ws + 24 * MB);    // fragment-ordered K, 8MB
  u16* Vf = (u16*)(ws + 32 * MB);    // fragment-ordered V, 8MB
  u16* Y = (u16*)(ws + 40 * MB);     // [4096][1024] 8MB

  prep_k<<<8192, 256, 0, stream>>>(x, xb, Wq, Wk, Wv, Wo, WcatT, WoT);
  gemm_k<0><<<dim3(24, 32), 512, 0, stream>>>(xb, WcatT, nullptr, Qf, Kf, Vf, rc, rs);
  attn_k<<<512, 256, 0, stream>>>(Qf, Kf, Vf, Y);
  gemm_k<1><<<dim3(8, 32), 512, 0, stream>>>(Y, WoT, out, nullptr, nullptr, nullptr, nullptr, nullptr);
}

// Round 18
// 104.480 us; speedup vs baseline: 1.0331x; 1.0331x over previous
//
#include <hip/hip_runtime.h>
#include <math.h>

typedef unsigned short u16;
typedef unsigned int u32;
typedef __bf16 bf16x8 __attribute__((ext_vector_type(8)));
typedef float f32x4 __attribute__((ext_vector_type(4)));
typedef unsigned short ushort4v __attribute__((ext_vector_type(4)));

#define T_SEQ 2048
#define WIN_M1 523                 // WINDOW-1
#define QSCALE 0.180336879f        // 0.125 * log2(e): scores end up in log2 domain
#define MASKV -1e30f

__device__ __forceinline__ u16 f2b(float f) {
  union { float f; unsigned int u; } v; v.f = f;
  unsigned int u = v.u;
  u += 0x7FFFu + ((u >> 16) & 1u);
  return (u16)(u >> 16);
}

__device__ __forceinline__ u32 cvtpk(float lo, float hi) {
  union { __bf16 h[2]; u32 d; } cv;
  cv.h[0] = (__bf16)lo;
  cv.h[1] = (__bf16)hi;
  return cv.d;
}

__device__ __forceinline__ float fexp2(float x) {
  return __builtin_amdgcn_exp2f(x);
}

__device__ __forceinline__ void load_lds16(const u16* g, u16* l) {
  __builtin_amdgcn_global_load_lds(
      (const __attribute__((address_space(1))) void*)g,
      (__attribute__((address_space(3))) void*)l, 16, 0, 0);
}

// ===================== FRAGMENT-ORDERED TENSOR LAYOUTS (R16 win) ===========
//   Qf/Kf: [bh][t16=t/16][kb(2)][q4(4)][l15(16)][e(8)]
//   Vf:    [bh][kv32=kv/32][jo(4)][q4(4)][l15(16)][e(8)]
// ===========================================================================

// ---- fused prep: convert x + transpose 4 weights ----
__global__ void prep_k(const float* __restrict__ x, u16* __restrict__ xb,
                       const float* __restrict__ W0, const float* __restrict__ W1,
                       const float* __restrict__ W2, const float* __restrict__ W3,
                       u16* __restrict__ WcatT, u16* __restrict__ WoT) {
  const int bid = blockIdx.x;
  if (bid < 4096) {
    int i = bid * 256 + threadIdx.x;
    float4 v = ((const float4*)x)[i];
    u16* d = xb + i * 4;
    d[0] = f2b(v.x); d[1] = f2b(v.y); d[2] = f2b(v.z); d[3] = f2b(v.w);
    return;
  }
  __shared__ float tile[32][33];
  const int t = bid - 4096;
  const int z = t >> 10, i = t & 1023;
  const float* W = (z == 0) ? W0 : (z == 1) ? W1 : (z == 2) ? W2 : W3;
  u16* Wt = (z < 3) ? (WcatT + (size_t)z * 1024 * 1024) : WoT;
  int tx = threadIdx.x & 31, ty = threadIdx.x >> 5;  // 32 x 8
  int n0 = (i & 31) * 32, k0 = (i >> 5) * 32;
#pragma unroll
  for (int j = 0; j < 4; ++j)
    tile[ty + j * 8][tx] = W[(size_t)(k0 + ty + j * 8) * 1024 + n0 + tx];
  __syncthreads();
#pragma unroll
  for (int j = 0; j < 4; ++j)
    Wt[(size_t)(n0 + ty + j * 8) * 1024 + k0 + tx] = f2b(tile[tx][ty + j * 8]);
}

// ---- QKV GEMM: 256x256 tile, 8 waves, 3-buf 96KB LDS, R16 vmcnt pipeline ----
// R18: gemm is L3-STAGING-BW bound (R17 data: gemm0 384MB/42us and gemm1
// 128MB/13us both = ~9.5 TB/s). 256^2 tile halves staged traffic to 192MB.
// Per wave: 64 rows (wm) x 128 cols (wn), acc[4][8]; stages 2 A + 2 B chunks
// (4 loads/step -> vmcnt(8)/(4)/(0) exactly as R16's proven ladder).
// A=xb[4096][1024], Bt=WcatT[3072][1024] -> Qf/Kf (rope) + Vf.
__global__ __launch_bounds__(512, 2) void gemm_qkv(
    const u16* __restrict__ A, const u16* __restrict__ Bt,
    u16* __restrict__ Qo, u16* __restrict__ Ko, u16* __restrict__ Vto,
    const float* __restrict__ rc, const float* __restrict__ rs) {
  __shared__ alignas(16) u16 As[3][256 * 32];
  __shared__ alignas(16) u16 Bs[3][256 * 32];
  const int tid = threadIdx.x, lane = tid & 63, w = tid >> 6;  // w 0..7
  const int l15 = lane & 15, q4 = lane >> 4;
  const int row0 = blockIdx.y * 256, col0 = blockIdx.x * 256;
  const int wm = w >> 1, wn = w & 1;  // wm 0..3 (64-row span), wn 0..1 (128-col span)
  constexpr int NT = 32;  // K=1024 / 32

  f32x4 acc[4][8];
#pragma unroll
  for (int i = 0; i < 4; ++i)
#pragma unroll
    for (int j = 0; j < 8; ++j) acc[i][j] = (f32x4){0.f, 0.f, 0.f, 0.f};

  // staging: tile [256 rows][32 k] = 16KB = 16 chunks of 1KB (16 rows each).
  // wave w stages chunks 2w, 2w+1 of A and of B. Lane: row c*16 + lane/4,
  // col(u16) (lane&3)*8 -> 16B.
  const int rs0 = w * 32 + (lane >> 2);
  const int rs1 = rs0 + 16;
  const int cs_ = (lane & 3) * 8;
  const u16* gA0 = A + (size_t)(row0 + rs0) * 1024 + cs_;
  const u16* gA1 = A + (size_t)(row0 + rs1) * 1024 + cs_;
  const u16* gB0 = Bt + (size_t)(col0 + rs0) * 1024 + cs_;
  const u16* gB1 = Bt + (size_t)(col0 + rs1) * 1024 + cs_;
  const int soff = w * 1024;  // u16 offset of chunk 2w in a buffer

  auto stage = [&](int buf, int t) {
    const int k0 = t * 32;
    load_lds16(gA0 + k0, &As[buf][soff]);
    load_lds16(gA1 + k0, &As[buf][soff + 512]);
    load_lds16(gB0 + k0, &Bs[buf][soff]);
    load_lds16(gB1 + k0, &Bs[buf][soff + 512]);
  };
  auto compute = [&](int buf) {
    bf16x8 af[4], bfr[8];
#pragma unroll
    for (int im = 0; im < 4; ++im)
      af[im] = *(const bf16x8*)&As[buf][(wm * 64 + im * 16 + l15) * 32 + q4 * 8];
#pragma unroll
    for (int jn = 0; jn < 8; ++jn)
      bfr[jn] = *(const bf16x8*)&Bs[buf][(wn * 128 + jn * 16 + l15) * 32 + q4 * 8];
#pragma unroll
    for (int im = 0; im < 4; ++im)
#pragma unroll
      for (int jn = 0; jn < 8; ++jn)
        acc[im][jn] = __builtin_amdgcn_mfma_f32_16x16x32_bf16(af[im], bfr[jn], acc[im][jn], 0, 0, 0);
  };

  stage(0, 0);
  stage(1, 1);
  int bs = 2, bc = 0;
  for (int t = 0; t + 2 < NT; ++t) {
    stage(bs, t + 2);
    asm volatile("s_waitcnt vmcnt(8)" ::: "memory");
    __builtin_amdgcn_s_barrier();
    compute(bc);
    __builtin_amdgcn_s_barrier();
    bs = (bs + 1 == 3) ? 0 : bs + 1;
    bc = (bc + 1 == 3) ? 0 : bc + 1;
  }
  asm volatile("s_waitcnt vmcnt(4)" ::: "memory");
  __builtin_amdgcn_s_barrier();
  compute(bc);
  __builtin_amdgcn_s_barrier();
  bc = (bc + 1 == 3) ? 0 : bc + 1;
  asm volatile("s_waitcnt vmcnt(0)" ::: "memory");
  __builtin_amdgcn_s_barrier();
  compute(bc);

  // Epilogue: RoPE Q/K + fragment-ordered scatter (R16-verified math).
  // jn pairs (x1 at jn, x2 at jn+2): jn in {0,1,4,5}. (nn&63)<32 holds for
  // these (col0,wn multiples of 64).
#pragma unroll
  for (int im = 0; im < 4; ++im) {
    const int rowb = row0 + wm * 64 + im * 16 + q4 * 4;
    const int b = rowb >> 11, t0 = rowb & 2047;
#pragma unroll
    for (int p = 0; p < 4; ++p) {
      const int jn = (p & 1) + (p >> 1) * 4;
      const int n = col0 + wn * 128 + jn * 16 + l15;
      const int sel = n >> 10, nn = n & 1023;
      const int h = nn >> 6, hd = nn & 63;  // hd in [0,32)
      const int bhi = b * 16 + h;
      if (sel < 2) {
        const float qs = (sel == 0) ? QSCALE : 1.0f;
        u16* base = (sel == 0 ? Qo : Ko);
        const int q4c = (hd >> 3) & 3, e = hd & 7;
#pragma unroll
        for (int r = 0; r < 4; ++r) {
          const int tt = t0 + r;
          const float c = rc[tt * 32 + hd], s = rs[tt * 32 + hd];
          const float x1 = acc[im][jn][r], x2 = acc[im][jn + 2][r];
          const size_t blk = ((size_t)bhi * 128 + (tt >> 4)) * 2;
          const size_t off = (size_t)q4c * 128 + (size_t)(tt & 15) * 8 + e;
          base[(blk << 9) + off] = f2b((x1 * c + x2 * s) * qs);
          base[((blk + 1) << 9) + off] = f2b((x1 * c - x2 * s) * qs);
        }
      } else {
        const int kv32 = t0 >> 5;
        const int q4w = (t0 >> 3) & 3;
        const int e0 = t0 & 7;           // in {0,4}
        const int jo1 = hd >> 4;
        const int l15r = hd & 15;
        ushort4v p1, p2;
#pragma unroll
        for (int r = 0; r < 4; ++r) {
          p1[r] = f2b(acc[im][jn][r]);
          p2[r] = f2b(acc[im][jn + 2][r]);
        }
        const size_t off = (size_t)q4w * 128 + (size_t)l15r * 8 + e0;
        const size_t b1 = ((((size_t)bhi * 64 + kv32) * 4 + jo1) << 9) + off;
        const size_t b2 = ((((size_t)bhi * 64 + kv32) * 4 + jo1 + 2) << 9) + off;
        *(ushort4v*)(Vto + b1) = p1;
        *(ushort4v*)(Vto + b2) = p2;
      }
    }
  }
}

// ---- out-proj GEMM: R16's proven 128x128 4-wave kernel (MODE 1 only) ----
__global__ __launch_bounds__(256, 4) void gemm_out(
    const u16* __restrict__ A, const u16* __restrict__ Bt,
    float* __restrict__ outf) {
  __shared__ alignas(16) u16 As[3][128 * 32];
  __shared__ alignas(16) u16 Bs[3][128 * 32];
  const int tid = threadIdx.x, lane = tid & 63, w = tid >> 6;
  const int l15 = lane & 15, q4 = lane >> 4;
  const int row0 = blockIdx.y * 128, col0 = blockIdx.x * 128;
  const int wm = w >> 1, wn = w & 1;
  constexpr int NT = 32;

  f32x4 acc[4][4];
#pragma unroll
  for (int i = 0; i < 4; ++i)
#pragma unroll
    for (int j = 0; j < 4; ++j) acc[i][j] = (f32x4){0.f, 0.f, 0.f, 0.f};

  const int off0 = (w * 2) * 1024 + lane * 16;
  const int r0 = off0 >> 6, c0 = (off0 & 63) >> 1;
  const int off1 = off0 + 1024;
  const int r1 = off1 >> 6, c1 = (off1 & 63) >> 1;
  const u16* gA0 = A + (size_t)(row0 + r0) * 1024 + c0;
  const u16* gA1 = A + (size_t)(row0 + r1) * 1024 + c1;
  const u16* gB0 = Bt + (size_t)(col0 + r0) * 1024 + c0;
  const u16* gB1 = Bt + (size_t)(col0 + r1) * 1024 + c1;
  const int soff = (w * 2) * 512;

  auto stage = [&](int buf, int t) {
    const int k0 = t * 32;
    load_lds16(gA0 + k0, &As[buf][soff]);
    load_lds16(gA1 + k0, &As[buf][soff + 512]);
    load_lds16(gB0 + k0, &Bs[buf][soff]);
    load_lds16(gB1 + k0, &Bs[buf][soff + 512]);
  };
  auto compute = [&](int buf) {
    bf16x8 af[4], bfr[4];
#pragma unroll
    for (int im = 0; im < 4; ++im)
      af[im] = *(const bf16x8*)&As[buf][(wm * 64 + im * 16 + l15) * 32 + q4 * 8];
#pragma unroll
    for (int jn = 0; jn < 4; ++jn)
      bfr[jn] = *(const bf16x8*)&Bs[buf][(wn * 64 + jn * 16 + l15) * 32 + q4 * 8];
#pragma unroll
    for (int im = 0; im < 4; ++im)
#pragma unroll
      for (int jn = 0; jn < 4; ++jn)
        acc[im][jn] = __builtin_amdgcn_mfma_f32_16x16x32_bf16(af[im], bfr[jn], acc[im][jn], 0, 0, 0);
  };

  stage(0, 0);
  stage(1, 1);
  int bs = 2, bc = 0;
  for (int t = 0; t + 2 < NT; ++t) {
    stage(bs, t + 2);
    asm volatile("s_waitcnt vmcnt(8)" ::: "memory");
    __builtin_amdgcn_s_barrier();
    compute(bc);
    __builtin_amdgcn_s_barrier();
    bs = (bs + 1 == 3) ? 0 : bs + 1;
    bc = (bc + 1 == 3) ? 0 : bc + 1;
  }
  asm volatile("s_waitcnt vmcnt(4)" ::: "memory");
  __builtin_amdgcn_s_barrier();
  compute(bc);
  __builtin_amdgcn_s_barrier();
  bc = (bc + 1 == 3) ? 0 : bc + 1;
  asm volatile("s_waitcnt vmcnt(0)" ::: "memory");
  __builtin_amdgcn_s_barrier();
  compute(bc);

#pragma unroll
  for (int im = 0; im < 4; ++im) {
    const int rowb = row0 + wm * 64 + im * 16 + q4 * 4;
#pragma unroll
    for (int jn = 0; jn < 4; ++jn) {
      const int n = col0 + wn * 64 + jn * 16 + l15;
#pragma unroll
      for (int r = 0; r < 4; ++r)
        outf[(size_t)(rowb + r) * 1024 + n] = acc[im][jn][r];
    }
  }
}

// ---------------- windowed flash attention (R16 winner, unchanged) ----------------
__global__ __launch_bounds__(256) void attn_k(
    const u16* __restrict__ Q, const u16* __restrict__ Kk,
    const u16* __restrict__ Vt, u16* __restrict__ Y) {
  const int lane = threadIdx.x & 63, w = threadIdx.x >> 6;
  const int l15 = lane & 15, q4 = lane >> 4;
  const int hw = blockIdx.x;                    // 0..511
  const int work = (hw & 7) * 64 + (hw >> 3);   // XCD-chunked: each XCD owns 4 bh
  const int bh = work >> 4;
  const int qt = 15 - (work & 15);              // heavy first
  const int q0 = qt * 128 + w * 32;
  const int qt16 = q0 >> 4;

  bf16x8 bq[2][2];
#pragma unroll
  for (int qs = 0; qs < 2; ++qs)
#pragma unroll
    for (int kb = 0; kb < 2; ++kb)
      bq[qs][kb] = *(const bf16x8*)(Q + ((((size_t)bh * 128 + qt16 + qs) * 2 + kb) << 9) + lane * 8);

  f32x4 o[2][4];
#pragma unroll
  for (int qs = 0; qs < 2; ++qs)
#pragma unroll
    for (int jo = 0; jo < 4; ++jo) o[qs][jo] = (f32x4){0.f, 0.f, 0.f, 0.f};
  float lp[2] = {0.f, 0.f};

  int s0 = q0 - WIN_M1; if (s0 < 0) s0 = 0; s0 &= ~31;
  const int srcA = l15 + ((q4 & 1) << 5);
  const int srcB = srcA + 16;
  const bool lowq4 = (q4 < 2);

  bf16x8 kc[2][2], kn[2][2];
  bf16x8 vc[4], vn[4];
#pragma unroll
  for (int ks = 0; ks < 2; ++ks)
#pragma unroll
    for (int kb = 0; kb < 2; ++kb)
      kc[ks][kb] = *(const bf16x8*)(Kk + ((((size_t)bh * 128 + (s0 >> 4) + ks) * 2 + kb) << 9) + lane * 8);
#pragma unroll
  for (int jo = 0; jo < 4; ++jo)
    vc[jo] = *(const bf16x8*)(Vt + ((((size_t)bh * 64 + (s0 >> 5)) * 4 + jo) << 9) + lane * 8);

  int kv0 = s0;

#define TILE_BODY(KC, VC, KN, VN)                                                      \
  {                                                                                    \
    const int kvn = kv0 + 32;                                                          \
    if (kvn <= q0) {                                                                   \
      _Pragma("unroll") for (int ks = 0; ks < 2; ++ks)                                 \
          _Pragma("unroll") for (int kb = 0; kb < 2; ++kb)                             \
              KN[ks][kb] = *(const bf16x8*)(Kk +                                       \
                  ((((size_t)bh * 128 + (kvn >> 4) + ks) * 2 + kb) << 9) + lane * 8);  \
      _Pragma("unroll") for (int jo = 0; jo < 4; ++jo)                                 \
          VN[jo] = *(const bf16x8*)(Vt +                                               \
              ((((size_t)bh * 64 + (kvn >> 5)) * 4 + jo) << 9) + lane * 8);            \
    }                                                                                  \
    f32x4 ss[2][2];                                                                    \
    _Pragma("unroll") for (int ks = 0; ks < 2; ++ks)                                   \
        _Pragma("unroll") for (int qs = 0; qs < 2; ++qs)                               \
            ss[ks][qs] = (f32x4){0.f, 0.f, 0.f, 0.f};                                  \
    _Pragma("unroll") for (int kb = 0; kb < 2; ++kb)                                   \
        _Pragma("unroll") for (int ks = 0; ks < 2; ++ks)                               \
            _Pragma("unroll") for (int qs = 0; qs < 2; ++qs)                           \
                ss[ks][qs] = __builtin_amdgcn_mfma_f32_16x16x32_bf16(                  \
                    KC[ks][kb], bq[qs][kb], ss[ks][qs], 0, 0, 0);                      \
    if ((kv0 + 32 > q0) || (kv0 < q0 - 492)) {                                         \
      _Pragma("unroll") for (int qs = 0; qs < 2; ++qs) {                               \
        const int tq = q0 + qs * 16 + l15;                                             \
        _Pragma("unroll") for (int ks = 0; ks < 2; ++ks)                               \
            _Pragma("unroll") for (int r = 0; r < 4; ++r) {                            \
          const int kv = kv0 + ks * 16 + q4 * 4 + r;                                   \
          if (kv > tq || kv < tq - WIN_M1) ss[ks][qs][r] = MASKV;                      \
        }                                                                              \
      }                                                                                \
    }                                                                                  \
    _Pragma("unroll") for (int qs = 0; qs < 2; ++qs) {                                 \
      float p[2][4];                                                                   \
      _Pragma("unroll") for (int ks = 0; ks < 2; ++ks)                                 \
          _Pragma("unroll") for (int r = 0; r < 4; ++r)                                \
              p[ks][r] = fexp2(ss[ks][qs][r]);                                         \
      lp[qs] += ((p[0][0] + p[0][1]) + (p[0][2] + p[0][3])) +                          \
                ((p[1][0] + p[1][1]) + (p[1][2] + p[1][3]));                           \
      const u32 a0 = cvtpk(p[0][0], p[0][1]), a1 = cvtpk(p[0][2], p[0][3]);            \
      const u32 b0 = cvtpk(p[1][0], p[1][1]), b1 = cvtpk(p[1][2], p[1][3]);            \
      union { u32 d[4]; bf16x8 v; } pu;                                                \
      const u32 d0a = (u32)__shfl((int)a0, srcA), d0b = (u32)__shfl((int)b0, srcA);    \
      const u32 d1a = (u32)__shfl((int)a1, srcA), d1b = (u32)__shfl((int)b1, srcA);    \
      const u32 d2a = (u32)__shfl((int)a0, srcB), d2b = (u32)__shfl((int)b0, srcB);    \
      const u32 d3a = (u32)__shfl((int)a1, srcB), d3b = (u32)__shfl((int)b1, srcB);    \
      pu.d[0] = lowq4 ? d0a : d0b;                                                     \
      pu.d[1] = lowq4 ? d1a : d1b;                                                     \
      pu.d[2] = lowq4 ? d2a : d2b;                                                     \
      pu.d[3] = lowq4 ? d3a : d3b;                                                     \
      _Pragma("unroll") for (int jo = 0; jo < 4; ++jo)                                 \
          o[qs][jo] = __builtin_amdgcn_mfma_f32_16x16x32_bf16(pu.v, VC[jo],            \
                                                              o[qs][jo], 0, 0, 0);     \
    }                                                                                  \
  }

  while (true) {
    TILE_BODY(kc, vc, kn, vn);
    kv0 += 32; if (kv0 > q0) break;
    TILE_BODY(kn, vn, kc, vc);
    kv0 += 32; if (kv0 > q0) break;
  }
#undef TILE_BODY

  const int b = bh >> 4, h = bh & 15;
  u16* Yb = Y + (size_t)(b * 2048 + q0) * 1024 + h * 64 + l15;
#pragma unroll
  for (int qs = 0; qs < 2; ++qs) {
    float l = lp[qs];
    l += __shfl_xor(l, 16);
    l += __shfl_xor(l, 32);
#pragma unroll
    for (int r = 0; r < 4; ++r) {
      const float lv = __shfl(l, q4 * 4 + r);
      const float inv = 1.0f / lv;
      u16* yr = Yb + (size_t)(qs * 16 + q4 * 4 + r) * 1024;
#pragma unroll
      for (int jo = 0; jo < 4; ++jo) yr[jo * 16] = f2b(o[qs][jo][r] * inv);
    }
  }
}

extern "C" void kernel_launch(void* const* d_in, const int* in_sizes, int n_in,
                              void* d_out, int out_size, void* d_ws, size_t ws_size,
                              hipStream_t stream) {
  const float* x = (const float*)d_in[0];
  const float* Wq = (const float*)d_in[1];
  const float* Wk = (const float*)d_in[2];
  const float* Wv = (const float*)d_in[3];
  const float* Wo = (const float*)d_in[4];
  const float* rc = (const float*)d_in[5];
  const float* rs = (const float*)d_in[6];
  float* out = (float*)d_out;
  char* ws = (char*)d_ws;
  const size_t MB = 1024 * 1024;
  u16* xb = (u16*)(ws);              // [4096][1024] 8MB
  u16* WcatT = (u16*)(ws + 8 * MB);  // [3072][1024] 6MB (Wq^T|Wk^T|Wv^T)
  u16* WoT = (u16*)(ws + 14 * MB);   // [1024][1024] 2MB
  u16* Qf = (u16*)(ws + 16 * MB);    // fragment-ordered Q, 8MB
  u16* Kf = (u16*)(ws + 24 * MB);    // fragment-ordered K, 8MB
  u16* Vf = (u16*)(ws + 32 * MB);    // fragment-ordered V, 8MB
  u16* Y = (u16*)(ws + 40 * MB);     // [4096][1024] 8MB

  prep_k<<<8192, 256, 0, stream>>>(x, xb, Wq, Wk, Wv, Wo, WcatT, WoT);
  gemm_qkv<<<dim3(12, 16), 512, 0, stream>>>(xb, WcatT, Qf, Kf, Vf, rc, rs);
  attn_k<<<512, 256, 0, stream>>>(Qf, Kf, Vf, Y);
  gemm_out<<<dim3(8, 32), 256, 0, stream>>>(Y, WoT, out);
}